// Round 1
// baseline (3123.697 us; speedup 1.0000x reference)
//
#include <hip/hip_runtime.h>

#define NDIM 16384

typedef __attribute__((ext_vector_type(4))) float floatx4;
typedef __attribute__((ext_vector_type(8))) __bf16 bf16x8;
typedef __attribute__((ext_vector_type(4))) __bf16 bf16x4;

__device__ __forceinline__ void async16(const void* g, void* l) {
    __builtin_amdgcn_global_load_lds(
        (const __attribute__((address_space(1))) void*)g,
        (__attribute__((address_space(3))) void*)l, 16, 0, 0);
}

__device__ __forceinline__ floatx4 mfma16(bf16x8 a, bf16x8 b, floatx4 c) {
    return __builtin_amdgcn_mfma_f32_16x16x32_bf16(a, b, c, 0, 0, 0);
}

// ---------------------------------------------------------------------------
// Transpose + convert: S fp32 [m][n] row-major -> St bf16 [n][m] row-major.
// 64x64 tiles through LDS (pad +1 to break bank conflicts on the column read).
// ---------------------------------------------------------------------------
__global__ __launch_bounds__(256) void k_transpose_convert(
    const float* __restrict__ S, __bf16* __restrict__ St) {
    __shared__ float tile[64][65];
    const int t = threadIdx.x;
    const int m0 = blockIdx.y * 64, n0 = blockIdx.x * 64;
    const int tr = t >> 4, tc = (t & 15) * 4;
#pragma unroll
    for (int j = 0; j < 4; j++) {
        const int row = j * 16 + tr;
        const float4 v = *(const float4*)&S[(size_t)(m0 + row) * NDIM + n0 + tc];
        tile[row][tc + 0] = v.x; tile[row][tc + 1] = v.y;
        tile[row][tc + 2] = v.z; tile[row][tc + 3] = v.w;
    }
    __syncthreads();
#pragma unroll
    for (int j = 0; j < 4; j++) {
        const int nrow = j * 16 + tr;
        bf16x4 o;
        o.x = (__bf16)tile[tc + 0][nrow];
        o.y = (__bf16)tile[tc + 1][nrow];
        o.z = (__bf16)tile[tc + 2][nrow];
        o.w = (__bf16)tile[tc + 3][nrow];
        *(bf16x4*)&St[(size_t)(n0 + nrow) * NDIM + m0 + tc] = o;
    }
}

// ---------------------------------------------------------------------------
// Thin GEMM (layer 1): C[16][N] += A[Ra][N](fp32) * S, via Bt = S^T bf16.
// Split-K by 2 (grid = 2*(N/64)), fp32 atomicAdd epilogue into pre-zeroed C.
// A rows >= Ra are staged as zeros.
// ---------------------------------------------------------------------------
__global__ __launch_bounds__(256) void k_gemm_thin(
    const float* __restrict__ A, const __bf16* __restrict__ Bt,
    float* __restrict__ C, int Ra) {
    __shared__ __align__(16) __bf16 sB[64 * 64];  // [n_local][k_local]
    __shared__ __align__(16) __bf16 sA[16 * 64];  // [r][k_local]
    const int t = threadIdx.x, w = t >> 6, l = t & 63;
    const int n0 = (blockIdx.x >> 1) * 64;
    const int kbeg = (blockIdx.x & 1) * (NDIM / 2);
    const int lr = l & 15, lq = l >> 4;
    floatx4 acc = {0.f, 0.f, 0.f, 0.f};

    for (int k0 = kbeg; k0 < kbeg + NDIM / 2; k0 += 64) {
        // stage B tile (64x64 bf16 = 8KB) via global_load_lds x2
#pragma unroll
        for (int j = 0; j < 2; j++) {
            const __bf16* g =
                &Bt[(size_t)(n0 + j * 32 + w * 8 + (l >> 3)) * NDIM + k0 + (l & 7) * 8];
            async16(g, &sB[j * 2048 + w * 512 + l * 8]);
        }
        // stage A tile (16x64) from fp32 with row guard, convert in regs
        {
            const int r = t >> 4, kc = (t & 15) * 4;
            float4 v = {0.f, 0.f, 0.f, 0.f};
            if (r < Ra) v = *(const float4*)&A[(size_t)r * NDIM + k0 + kc];
            bf16x4 o;
            o.x = (__bf16)v.x; o.y = (__bf16)v.y; o.z = (__bf16)v.z; o.w = (__bf16)v.w;
            *(bf16x4*)&sA[r * 64 + kc] = o;
        }
        __syncthreads();
#pragma unroll
        for (int kk = 0; kk < 64; kk += 32) {
            bf16x8 a = *(const bf16x8*)&sA[lr * 64 + kk + lq * 8];
            bf16x8 b = *(const bf16x8*)&sB[(16 * w + lr) * 64 + kk + lq * 8];
            acc = mfma16(a, b, acc);
        }
        __syncthreads();
    }
#pragma unroll
    for (int v = 0; v < 4; v++)
        atomicAdd(&C[(size_t)(lq * 4 + v) * NDIM + n0 + 16 * w + lr], acc[v]);
}

// ---------------------------------------------------------------------------
// Wide GEMM (layer 2): C[128][N] = A[128][N](bf16) * S, via Bt = S^T bf16.
// C-tile 128x64, 4 waves x (2 row-tiles x 4 col-tiles), double-buffered LDS.
// ---------------------------------------------------------------------------
__global__ __launch_bounds__(256) void k_gemm_wide(
    const __bf16* __restrict__ A, const __bf16* __restrict__ Bt,
    __bf16* __restrict__ C) {
    __shared__ __align__(16) __bf16 sA[2][128 * 64];  // 2 x 16KB
    __shared__ __align__(16) __bf16 sB[2][64 * 64];   // 2 x 8KB
    const int t = threadIdx.x, w = t >> 6, l = t & 63;
    const int n0 = blockIdx.x * 64;
    const int lr = l & 15, lq = l >> 4;

    floatx4 acc[2][4];
#pragma unroll
    for (int i = 0; i < 2; i++)
#pragma unroll
        for (int c = 0; c < 4; c++) acc[i][c] = (floatx4){0.f, 0.f, 0.f, 0.f};

    auto stage = [&](int buf, int k0) {
#pragma unroll
        for (int j = 0; j < 4; j++) {
            const __bf16* g =
                &A[(size_t)(j * 32 + w * 8 + (l >> 3)) * NDIM + k0 + (l & 7) * 8];
            async16(g, &sA[buf][j * 2048 + w * 512 + l * 8]);
        }
#pragma unroll
        for (int j = 0; j < 2; j++) {
            const __bf16* g =
                &Bt[(size_t)(n0 + j * 32 + w * 8 + (l >> 3)) * NDIM + k0 + (l & 7) * 8];
            async16(g, &sB[buf][j * 2048 + w * 512 + l * 8]);
        }
    };

    stage(0, 0);
    int buf = 0;
    for (int kb = 0; kb < NDIM / 64; kb++) {
        __syncthreads();  // drains own vmcnt -> staged buf ready; prev compute done
        if (kb + 1 < NDIM / 64) stage(buf ^ 1, (kb + 1) * 64);
#pragma unroll
        for (int kk = 0; kk < 64; kk += 32) {
            bf16x8 a0 = *(const bf16x8*)&sA[buf][(32 * w + lr) * 64 + kk + lq * 8];
            bf16x8 a1 = *(const bf16x8*)&sA[buf][(32 * w + 16 + lr) * 64 + kk + lq * 8];
#pragma unroll
            for (int c = 0; c < 4; c++) {
                bf16x8 b = *(const bf16x8*)&sB[buf][(16 * c + lr) * 64 + kk + lq * 8];
                acc[0][c] = mfma16(a0, b, acc[0][c]);
                acc[1][c] = mfma16(a1, b, acc[1][c]);
            }
        }
        buf ^= 1;
    }
#pragma unroll
    for (int i = 0; i < 2; i++)
#pragma unroll
        for (int c = 0; c < 4; c++)
#pragma unroll
            for (int v = 0; v < 4; v++)
                C[(size_t)(32 * w + 16 * i + lq * 4 + v) * NDIM + n0 + 16 * c + lr] =
                    (__bf16)acc[i][c][v];
}

// ---------------------------------------------------------------------------
// Layer-1 tap combine: Y1[b*16+g][n] = relu(b1[g] + sum_k H1[g,k,0]*Zk[b][n])
// ---------------------------------------------------------------------------
__global__ __launch_bounds__(256) void k_tap1(
    const float* __restrict__ x, const float* __restrict__ Z1,
    const float* __restrict__ Z2, const float* __restrict__ Z3,
    const float* __restrict__ H1, const float* __restrict__ b1,
    __bf16* __restrict__ Y1) {
    const int idx = blockIdx.x * 256 + threadIdx.x;  // b*N + n
    const int b = idx >> 14, n = idx & (NDIM - 1);
    float z[4] = {x[idx], Z1[idx], Z2[idx], Z3[idx]};
#pragma unroll
    for (int g = 0; g < 16; g++) {
        float y = b1[g];
#pragma unroll
        for (int k = 0; k < 4; k++) y += H1[g * 4 + k] * z[k];
        y = fmaxf(y, 0.f);
        Y1[(size_t)(b * 16 + g) * NDIM + n] = (__bf16)y;
    }
}

// ---------------------------------------------------------------------------
// Layer-2 tap combine + readout, fused:
// y2[g] = relu(b2[g] + sum_{k,f} H2[g,k,f]*Wk[b*16+f][n])
// out[b,r,n] = bro[r] + sum_g Wro[r,g]*y2[g]
// ---------------------------------------------------------------------------
__global__ __launch_bounds__(256) void k_tap2_readout(
    const __bf16* __restrict__ W0, const __bf16* __restrict__ W1,
    const __bf16* __restrict__ W2, const __bf16* __restrict__ W3,
    const float* __restrict__ H2, const float* __restrict__ b2,
    const float* __restrict__ Wro, const float* __restrict__ bro,
    float* __restrict__ out) {
    const int idx = blockIdx.x * 256 + threadIdx.x;  // b*N + n
    const int b = idx >> 14, n = idx & (NDIM - 1);
    float pre[16];
#pragma unroll
    for (int g = 0; g < 16; g++) pre[g] = b2[g];
    const __bf16* Ws[4] = {W0, W1, W2, W3};
#pragma unroll
    for (int k = 0; k < 4; k++) {
#pragma unroll
        for (int f = 0; f < 16; f++) {
            const float wv = (float)Ws[k][(size_t)(b * 16 + f) * NDIM + n];
#pragma unroll
            for (int g = 0; g < 16; g++) pre[g] += H2[(g * 4 + k) * 16 + f] * wv;
        }
    }
#pragma unroll
    for (int r = 0; r < 8; r++) {
        float o = bro[r];
#pragma unroll
        for (int g = 0; g < 16; g++) o += Wro[r * 16 + g] * fmaxf(pre[g], 0.f);
        out[(size_t)(b * 8 + r) * NDIM + n] = o;
    }
}

// ---------------------------------------------------------------------------
extern "C" void kernel_launch(void* const* d_in, const int* in_sizes, int n_in,
                              void* d_out, int out_size, void* d_ws, size_t ws_size,
                              hipStream_t stream) {
    const float* x   = (const float*)d_in[0];
    const float* S   = (const float*)d_in[1];
    const float* H1  = (const float*)d_in[2];
    const float* b1  = (const float*)d_in[3];
    const float* H2  = (const float*)d_in[4];
    const float* b2  = (const float*)d_in[5];
    const float* Wro = (const float*)d_in[6];
    const float* bro = (const float*)d_in[7];
    float* out = (float*)d_out;

    char* ws = (char*)d_ws;
    size_t off = 0;
    __bf16* St = (__bf16*)(ws + off); off += (size_t)NDIM * NDIM * 2;       // 512MB
    float* Z1  = (float*)(ws + off);  off += (size_t)16 * NDIM * 4;
    float* Z2  = (float*)(ws + off);  off += (size_t)16 * NDIM * 4;
    float* Z3  = (float*)(ws + off);  off += (size_t)16 * NDIM * 4;
    __bf16* Y1 = (__bf16*)(ws + off); off += (size_t)128 * NDIM * 2;
    __bf16* W1 = (__bf16*)(ws + off); off += (size_t)128 * NDIM * 2;
    __bf16* W2 = (__bf16*)(ws + off); off += (size_t)128 * NDIM * 2;
    __bf16* W3 = (__bf16*)(ws + off); off += (size_t)128 * NDIM * 2;

    // zero the atomic accumulators Z1..Z3 (contiguous)
    hipMemsetAsync(Z1, 0, (size_t)3 * 16 * NDIM * 4, stream);

    k_transpose_convert<<<dim3(256, 256), 256, 0, stream>>>(S, St);

    // layer-1 shift chain: Zk = Z(k-1) * S, rows = 8 (padded to 16)
    k_gemm_thin<<<512, 256, 0, stream>>>(x,  St, Z1, 8);
    k_gemm_thin<<<512, 256, 0, stream>>>(Z1, St, Z2, 8);
    k_gemm_thin<<<512, 256, 0, stream>>>(Z2, St, Z3, 8);

    k_tap1<<<512, 256, 0, stream>>>(x, Z1, Z2, Z3, H1, b1, Y1);

    // layer-2 shift chain: Wk = W(k-1) * S, 128 rows
    k_gemm_wide<<<256, 256, 0, stream>>>(Y1, St, W1);
    k_gemm_wide<<<256, 256, 0, stream>>>(W1, St, W2);
    k_gemm_wide<<<256, 256, 0, stream>>>(W2, St, W3);

    k_tap2_readout<<<512, 256, 0, stream>>>(Y1, W1, W2, W3, H2, b2, Wro, bro, out);
}